// Round 1
// baseline (290.531 us; speedup 1.0000x reference)
//
#include <hip/hip_runtime.h>
#include <stdint.h>

#define BATCH 4
#define SEQ 2048
#define NX 1024
#define NHEAD 16
#define HDIM 64
#define NTOK (BATCH * SEQ)   // 8192
#define QKV_LD (3 * NX)      // 3072

typedef __bf16 bf16_t;
typedef __bf16 bf16x8 __attribute__((ext_vector_type(8)));
typedef __bf16 bf16x4 __attribute__((ext_vector_type(4)));
typedef float  f32x4  __attribute__((ext_vector_type(4)));
typedef unsigned int u32x4 __attribute__((ext_vector_type(4)));

// ---------------- cast f32 -> bf16 (vectorized) ----------------
__global__ __launch_bounds__(256) void k_cast_bf16(const float* __restrict__ in,
                                                   bf16_t* __restrict__ out, int n4) {
  int stride = gridDim.x * blockDim.x;
  for (int i = blockIdx.x * blockDim.x + threadIdx.x; i < n4; i += stride) {
    f32x4 v = ((const f32x4*)in)[i];
    bf16x4 o;
    o[0] = (bf16_t)v[0]; o[1] = (bf16_t)v[1];
    o[2] = (bf16_t)v[2]; o[3] = (bf16_t)v[3];
    ((bf16x4*)out)[i] = o;
  }
}

// ---------------- transpose + cast: in[K][N] f32 -> out[N][K] bf16 ----------------
__global__ __launch_bounds__(256) void k_transpose_cast(const float* __restrict__ in,
                                                        bf16_t* __restrict__ out,
                                                        int K, int N) {
  __shared__ float tile[32][33];
  const int kb = blockIdx.x * 32, nb = blockIdx.y * 32;
  const int tx = threadIdx.x & 31;
  const int ty = (threadIdx.x >> 5) * 4;
#pragma unroll
  for (int i = 0; i < 4; i++)
    tile[ty + i][tx] = in[(size_t)(kb + ty + i) * N + nb + tx];
  __syncthreads();
#pragma unroll
  for (int i = 0; i < 4; i++)
    out[(size_t)(nb + ty + i) * K + kb + tx] = (bf16_t)tile[tx][ty + i];
}

// ---------------- GEMM: C[M][N] = A[M][K] * Bt[N][K]^T + bias ----------------
// 128x128 tile, BK=32, 256 threads (4 waves 2x2, 64x64 per wave), mfma 16x16x32 bf16
template <int OUT_BF16>
__global__ __launch_bounds__(256) void k_gemm_bt(const bf16_t* __restrict__ A,
                                                 const bf16_t* __restrict__ Bt,
                                                 const float* __restrict__ bias,
                                                 void* __restrict__ Cout,
                                                 int M, int N, int K) {
  __shared__ __align__(16) bf16_t lsA[128 * 32];
  __shared__ __align__(16) bf16_t lsB[128 * 32];
  const int tid  = threadIdx.x;
  const int lane = tid & 63;
  const int wid  = tid >> 6;
  const int wr   = wid >> 1, wc = wid & 1;
  const int m0 = blockIdx.x * 128, n0 = blockIdx.y * 128;

  const int srow = tid >> 2;          // 0..63
  const int scol = (tid & 3) * 8;     // 0,8,16,24
  const bf16_t* Ap = A  + (size_t)(m0 + srow) * K + scol;
  const bf16_t* Bp = Bt + (size_t)(n0 + srow) * K + scol;

  f32x4 acc[4][4];
#pragma unroll
  for (int i = 0; i < 4; i++)
#pragma unroll
    for (int j = 0; j < 4; j++) acc[i][j] = (f32x4){0.f, 0.f, 0.f, 0.f};

  const int fr = lane & 15;
  const int kb = (lane >> 4) * 8;

  for (int k0 = 0; k0 < K; k0 += 32) {
    *(u32x4*)&lsA[srow * 32 + scol]        = *(const u32x4*)(Ap + k0);
    *(u32x4*)&lsA[(srow + 64) * 32 + scol] = *(const u32x4*)(Ap + (size_t)64 * K + k0);
    *(u32x4*)&lsB[srow * 32 + scol]        = *(const u32x4*)(Bp + k0);
    *(u32x4*)&lsB[(srow + 64) * 32 + scol] = *(const u32x4*)(Bp + (size_t)64 * K + k0);
    __syncthreads();
    bf16x8 af[4], bfr[4];
#pragma unroll
    for (int mf = 0; mf < 4; mf++)
      af[mf] = *(const bf16x8*)&lsA[(wr * 64 + mf * 16 + fr) * 32 + kb];
#pragma unroll
    for (int nf = 0; nf < 4; nf++)
      bfr[nf] = *(const bf16x8*)&lsB[(wc * 64 + nf * 16 + fr) * 32 + kb];
#pragma unroll
    for (int mf = 0; mf < 4; mf++)
#pragma unroll
      for (int nf = 0; nf < 4; nf++)
        acc[mf][nf] = __builtin_amdgcn_mfma_f32_16x16x32_bf16(af[mf], bfr[nf], acc[mf][nf], 0, 0, 0);
    __syncthreads();
  }

  // C/D layout: col = lane&15, row = (lane>>4)*4 + reg
  const int col = lane & 15, rb = (lane >> 4) * 4;
#pragma unroll
  for (int mf = 0; mf < 4; mf++) {
#pragma unroll
    for (int nf = 0; nf < 4; nf++) {
      const int gm = m0 + wr * 64 + mf * 16 + rb;
      const int gn = n0 + wc * 64 + nf * 16 + col;
      const float bv = bias[gn];
#pragma unroll
      for (int r = 0; r < 4; r++) {
        float v = acc[mf][nf][r] + bv;
        if (OUT_BF16)
          ((bf16_t*)Cout)[(size_t)(gm + r) * N + gn] = (bf16_t)v;
        else
          ((float*)Cout)[(size_t)(gm + r) * N + gn] = v;
      }
    }
  }
}

// ---------------- causal flash attention ----------------
// 1 wave per (b, h, 32 q-rows). qkv: [NTOK][3072] bf16, att out: [NTOK][1024] bf16.
// S^T = mfma(K_rows, Q^T) with permuted K rows so S^T C-regs ARE the PV A-frag.
__global__ __launch_bounds__(64) void k_attn(const bf16_t* __restrict__ qkv,
                                             bf16_t* __restrict__ attout) {
  const int lane = threadIdx.x;
  const int blk  = blockIdx.x;
  const int qt   = 63 - (blk & 63);   // heavy tiles first
  const int bh   = blk >> 6;
  const int b    = bh >> 4, h = bh & 15;
  const bf16_t* Qb = qkv + (size_t)b * SEQ * QKV_LD + h * HDIM;
  const bf16_t* Kb = Qb + NX;
  const bf16_t* Vb = Qb + 2 * NX;
  const int q0 = qt * 32;

  const int fr  = lane & 15;
  const int g2  = lane >> 4;       // 0..3
  const int kb8 = g2 * 8;

  // Q b-frags (pre-scaled by 1/sqrt(64)=0.125, exact in bf16)
  bf16x8 bq[2][2];
#pragma unroll
  for (int g = 0; g < 2; g++)
#pragma unroll
    for (int kf = 0; kf < 2; kf++) {
      bf16x8 t = *(const bf16x8*)&Qb[(size_t)(q0 + g * 16 + fr) * QKV_LD + kf * 32 + kb8];
#pragma unroll
      for (int j = 0; j < 8; j++) t[j] = (bf16_t)((float)t[j] * 0.125f);
      bq[g][kf] = t;
    }

  // permuted K row for sub-tile A: C-reg r at lane-group g2 then holds kv = kv0 + 8*g2 + r
  const int permA = (fr & 3) + 8 * (fr >> 2);

  float m_run[2] = {-1e30f, -1e30f};
  float l_run[2] = {0.f, 0.f};
  f32x4 o[2][4];
#pragma unroll
  for (int g = 0; g < 2; g++)
#pragma unroll
    for (int d = 0; d < 4; d++) o[g][d] = (f32x4){0.f, 0.f, 0.f, 0.f};

  for (int kv0 = 0; kv0 <= q0; kv0 += 32) {
    bf16x8 akA[2], akB[2];
#pragma unroll
    for (int kf = 0; kf < 2; kf++) {
      akA[kf] = *(const bf16x8*)&Kb[(size_t)(kv0 + permA) * QKV_LD + kf * 32 + kb8];
      akB[kf] = *(const bf16x8*)&Kb[(size_t)(kv0 + permA + 4) * QKV_LD + kf * 32 + kb8];
    }
    // V b-frags: vb[df][j] = V[kv0 + 8*g2 + j][df*16 + fr]
    bf16x8 vb[4];
#pragma unroll
    for (int df = 0; df < 4; df++)
#pragma unroll
      for (int j = 0; j < 8; j++)
        vb[df][j] = Vb[(size_t)(kv0 + g2 * 8 + j) * QKV_LD + df * 16 + fr];

    bf16x8 pa[2];
    float alpha_s[2];
#pragma unroll
    for (int g = 0; g < 2; g++) {
      f32x4 sA = (f32x4){0.f, 0.f, 0.f, 0.f};
      f32x4 sB = (f32x4){0.f, 0.f, 0.f, 0.f};
      sA = __builtin_amdgcn_mfma_f32_16x16x32_bf16(akA[0], bq[g][0], sA, 0, 0, 0);
      sA = __builtin_amdgcn_mfma_f32_16x16x32_bf16(akA[1], bq[g][1], sA, 0, 0, 0);
      sB = __builtin_amdgcn_mfma_f32_16x16x32_bf16(akB[0], bq[g][0], sB, 0, 0, 0);
      sB = __builtin_amdgcn_mfma_f32_16x16x32_bf16(akB[1], bq[g][1], sB, 0, 0, 0);
      const int q_abs = q0 + g * 16 + fr;   // this lane's q column
      float sv[8], tmax = -1e30f;
#pragma unroll
      for (int r = 0; r < 4; r++) {
        const int kvA = kv0 + g2 * 8 + r;
        const int kvB = kvA + 4;
        float xA = (kvA <= q_abs) ? sA[r] : -1e30f;
        float xB = (kvB <= q_abs) ? sB[r] : -1e30f;
        sv[r] = xA; sv[r + 4] = xB;
        tmax = fmaxf(tmax, fmaxf(xA, xB));
      }
      tmax = fmaxf(tmax, __shfl_xor(tmax, 16));
      tmax = fmaxf(tmax, __shfl_xor(tmax, 32));
      const float m_new = fmaxf(m_run[g], tmax);
      const float alpha = __expf(m_run[g] - m_new);
      float tsum = 0.f;
      bf16x8 p;
#pragma unroll
      for (int j = 0; j < 8; j++) {
        float pv = __expf(sv[j] - m_new);
        tsum += pv;
        p[j] = (bf16_t)pv;
      }
      tsum += __shfl_xor(tsum, 16);
      tsum += __shfl_xor(tsum, 32);
      l_run[g] = l_run[g] * alpha + tsum;
      m_run[g] = m_new;
      pa[g] = p;
      alpha_s[g] = alpha;
    }
    // O rescale (alpha lives at lane q; O row q_local = g2*4+r) + PV
#pragma unroll
    for (int g = 0; g < 2; g++) {
#pragma unroll
      for (int r = 0; r < 4; r++) {
        const float ab = __shfl(alpha_s[g], g2 * 4 + r);
#pragma unroll
        for (int df = 0; df < 4; df++) o[g][df][r] *= ab;
      }
#pragma unroll
      for (int df = 0; df < 4; df++)
        o[g][df] = __builtin_amdgcn_mfma_f32_16x16x32_bf16(pa[g], vb[df], o[g][df], 0, 0, 0);
    }
  }

  // epilogue: divide by l, store bf16 to [tok][h*64 + d]
#pragma unroll
  for (int g = 0; g < 2; g++) {
    const float inv = 1.f / l_run[g];
#pragma unroll
    for (int r = 0; r < 4; r++) {
      const float iv = __shfl(inv, g2 * 4 + r);
      const int tok = b * SEQ + q0 + g * 16 + g2 * 4 + r;
#pragma unroll
      for (int df = 0; df < 4; df++)
        attout[(size_t)tok * NX + h * HDIM + df * 16 + fr] = (bf16_t)(o[g][df][r] * iv);
    }
  }
}

// ---------------- launch ----------------
extern "C" void kernel_launch(void* const* d_in, const int* in_sizes, int n_in,
                              void* d_out, int out_size, void* d_ws, size_t ws_size,
                              hipStream_t stream) {
  const float* x      = (const float*)d_in[0];
  const float* w_attn = (const float*)d_in[1];
  const float* b_attn = (const float*)d_in[2];
  const float* w_proj = (const float*)d_in[3];
  const float* b_proj = (const float*)d_in[4];
  float* out = (float*)d_out;

  char* ws = (char*)d_ws;
  bf16_t* xb  = (bf16_t*)ws;                   // 16 MiB, reused as att
  bf16_t* wab = (bf16_t*)(ws + (16u << 20));   //  6 MiB, reused as wpb
  bf16_t* qkv = (bf16_t*)(ws + (22u << 20));   // 48 MiB   (peak ws use: 70 MiB)
  bf16_t* att = xb;
  bf16_t* wpb = wab;

  k_cast_bf16<<<2048, 256, 0, stream>>>(x, xb, NTOK * NX / 4);
  k_transpose_cast<<<dim3(NX / 32, (3 * NX) / 32), 256, 0, stream>>>(w_attn, wab, NX, 3 * NX);
  k_gemm_bt<1><<<dim3(NTOK / 128, (3 * NX) / 128), 256, 0, stream>>>(
      xb, wab, b_attn, (void*)qkv, NTOK, 3 * NX, NX);
  // xb dead from here; wab dead from here
  k_transpose_cast<<<dim3(NX / 32, NX / 32), 256, 0, stream>>>(w_proj, wpb, NX, NX);
  k_attn<<<BATCH * NHEAD * (SEQ / 32), 64, 0, stream>>>(qkv, att);
  k_gemm_bt<0><<<dim3(NTOK / 128, NX / 128), 256, 0, stream>>>(
      att, wpb, b_proj, d_out, NTOK, NX, NX);
}